// Round 5
// baseline (206.405 us; speedup 1.0000x reference)
//
#include <hip/hip_runtime.h>

#define N_TOK  8192
#define KDIM   4096
#define NE     16
#define NSLICE 32                  // k-slices -> 1024 blocks = 4/CU, 16 waves/CU
#define KS     (KDIM / NSLICE)     // 128 k per thread
#define NBATCH (KS / 32)           // 4 batches of 32 floats (128 B) per thread

// Partial logits, pure streaming: thread <-> token, no LDS, no barriers.
// Each lane reads its own token row in 128 B batches (8 x float4 issued
// back-to-back), so every 128 B line is fetched once and fully consumed --
// no over-fetch despite the 16 KB stride between lanes. gate rows are
// wave-uniform -> scalar loads. acc[16] + 8 staged float4 ~= 60 VGPR ->
// high occupancy; TLP (16 waves/CU) hides HBM latency.
__global__ void router_partial(const float* __restrict__ x,
                               const float* __restrict__ gate,
                               float* __restrict__ ws) {
  const int tid = threadIdx.x;
  const int g   = blockIdx.x >> 5;           // token group (32)
  const int s   = blockIdx.x & 31;           // k-slice (32)
  const int t   = g * 256 + tid;
  const int k0  = s * KS;
  const float4* xp = (const float4*)(x + (size_t)t * KDIM + k0);

  float acc[NE];
#pragma unroll
  for (int e = 0; e < NE; ++e) acc[e] = 0.f;

  for (int c = 0; c < NBATCH; ++c) {
    // batch-load one full 128 B line per lane (8 consecutive float4)
    float4 v[8];
#pragma unroll
    for (int i = 0; i < 8; ++i) v[i] = xp[c * 8 + i];
#pragma unroll
    for (int i = 0; i < 8; ++i) {
      const float xv[4] = {v[i].x, v[i].y, v[i].z, v[i].w};
#pragma unroll
      for (int m = 0; m < 4; ++m) {
        // wave-uniform row -> s_load_dwordx16
        const float* grow = gate + (size_t)(k0 + c * 32 + i * 4 + m) * NE;
#pragma unroll
        for (int e = 0; e < NE; ++e) acc[e] = fmaf(xv[m], grow[e], acc[e]);
      }
    }
  }

  // one 64 B store per thread: ws[s][t][0:16]
  float4* wp = (float4*)(ws + ((size_t)s * N_TOK + t) * NE);
  wp[0] = make_float4(acc[0],  acc[1],  acc[2],  acc[3]);
  wp[1] = make_float4(acc[4],  acc[5],  acc[6],  acc[7]);
  wp[2] = make_float4(acc[8],  acc[9],  acc[10], acc[11]);
  wp[3] = make_float4(acc[12], acc[13], acc[14], acc[15]);
}

// Sum 32 slice partials, top-2 (earliest-index tie-break = jax top_k),
// sigmoid, scatter into (E,N) scores; token_indices[e][t] = t (as float).
__global__ __launch_bounds__(256)
void router_finalize(const float* __restrict__ ws, float* __restrict__ out) {
  int t = blockIdx.x * 256 + threadIdx.x;
  float l[NE];
#pragma unroll
  for (int e = 0; e < NE; ++e) l[e] = 0.f;
  for (int s = 0; s < NSLICE; ++s) {
    const float4* row = (const float4*)(ws + ((size_t)s * N_TOK + t) * NE);
    float4 r0 = row[0], r1 = row[1], r2 = row[2], r3 = row[3];
    l[0]  += r0.x; l[1]  += r0.y; l[2]  += r0.z; l[3]  += r0.w;
    l[4]  += r1.x; l[5]  += r1.y; l[6]  += r1.z; l[7]  += r1.w;
    l[8]  += r2.x; l[9]  += r2.y; l[10] += r2.z; l[11] += r2.w;
    l[12] += r3.x; l[13] += r3.y; l[14] += r3.z; l[15] += r3.w;
  }
  int i1 = 0; float v1 = l[0];
#pragma unroll
  for (int e = 1; e < NE; ++e) { if (l[e] > v1) { v1 = l[e]; i1 = e; } }
  int i2 = -1; float v2 = -1e30f;
#pragma unroll
  for (int e = 0; e < NE; ++e) { if (e != i1 && l[e] > v2) { v2 = l[e]; i2 = e; } }
  float s1 = 1.f / (1.f + __expf(-v1));
  float s2 = 1.f / (1.f + __expf(-v2));
  float* scores = out;
  float* tix    = out + (size_t)NE * N_TOK;
  float tf = (float)t;
#pragma unroll
  for (int e = 0; e < NE; ++e) {             // coalesced across lanes per e
    scores[(size_t)e * N_TOK + t] = (e == i1) ? s1 : ((e == i2) ? s2 : 0.f);
    tix[(size_t)e * N_TOK + t]    = tf;
  }
}

extern "C" void kernel_launch(void* const* d_in, const int* in_sizes, int n_in,
                              void* d_out, int out_size, void* d_ws, size_t ws_size,
                              hipStream_t stream) {
  const float* x    = (const float*)d_in[0];
  const float* gate = (const float*)d_in[1];
  float* out = (float*)d_out;
  float* ws  = (float*)d_ws;   // needs NSLICE*N_TOK*NE*4 = 16 MB
  router_partial<<<dim3(N_TOK / 256 * NSLICE), dim3(256), 0, stream>>>(x, gate, ws);
  router_finalize<<<dim3(N_TOK / 256), dim3(256), 0, stream>>>(ws, out);
}